// Round 1
// baseline (827.922 us; speedup 1.0000x reference)
//
#include <hip/hip_runtime.h>
#include <math.h>

#define B_ 16
#define T_ 512
#define C_ 464
#define H_ 16
#define D_ 29
#define BT_ (B_*T_)      // 8192
#define N_QKV (3*C_)     // 1392
#define C4_ (4*C_)       // 1856

// ---------------- prep: wq/wk/wv (H,C,D) -> Wqkv (C, 3C) ----------------
__global__ void prep_wqkv(const float* __restrict__ wq, const float* __restrict__ wk,
                          const float* __restrict__ wv, float* __restrict__ W) {
  int idx = blockIdx.x * 256 + threadIdx.x;
  const int per = C_ * C_;
  if (idx >= 3 * per) return;
  int which = idx / per;
  int rem = idx - which * per;
  int c = rem / C_;
  int hd = rem - c * C_;
  int h = hd / D_;
  int d = hd - h * D_;
  const float* src = (which == 0) ? wq : (which == 1) ? wk : wv;
  W[(size_t)c * N_QKV + which * C_ + hd] = src[((size_t)h * C_ + c) * D_ + d];
}

// ---------------- rmsnorm: one block (128 thr) per row of 464 ----------------
__launch_bounds__(128)
__global__ void rmsnorm_kernel(const float* __restrict__ X, const float* __restrict__ g,
                               float* __restrict__ Y) {
  const int row = blockIdx.x;
  const int tid = threadIdx.x;
  __shared__ float red[2];
  const float4* x4 = (const float4*)(X + (size_t)row * C_);
  float4 v = make_float4(0.f,0.f,0.f,0.f);
  float ss = 0.f;
  if (tid < C_/4) { v = x4[tid]; ss = v.x*v.x + v.y*v.y + v.z*v.z + v.w*v.w; }
  #pragma unroll
  for (int off = 32; off > 0; off >>= 1) ss += __shfl_xor(ss, off);
  if ((tid & 63) == 0) red[tid >> 6] = ss;
  __syncthreads();
  float rs = rsqrtf((red[0] + red[1]) * (1.f / C_) + 1e-5f);
  if (tid < C_/4) {
    float4 gg = ((const float4*)g)[tid];
    float4 y;
    y.x = v.x * rs * gg.x; y.y = v.y * rs * gg.y;
    y.z = v.z * rs * gg.z; y.w = v.w * rs * gg.w;
    ((float4*)(Y + (size_t)row * C_))[tid] = y;
  }
}

// ---------------- f32 SGEMM 128x128x16, 256 thr, 8x8/thread ----------------
// EPI: 0 = plain, 1 = res + bias, 2 = silu, 3 = res
template<int EPI>
__launch_bounds__(256)
__global__ void gemm_f32(const float* __restrict__ A, const float* __restrict__ Bm,
                         float* __restrict__ C, const float* __restrict__ res,
                         const float* __restrict__ bias, int M, int N, int K) {
  __shared__ float As[16][128];
  __shared__ float Bs[16][128];
  const int tid = threadIdx.x;
  const int bm = blockIdx.x * 128;
  const int bn = blockIdx.y * 128;
  const int tx = tid & 15;
  const int ty = tid >> 4;
  const int ar = tid >> 1;           // A row within tile 0..127
  const int ak = (tid & 1) * 8;      // A k-offset 0 or 8
  const int br = tid >> 4;           // B k-row 0..15
  const int bc = (tid & 15) * 8;     // B col 0..120  (== tx*8)
  const bool bok = (bn + bc) < N;    // N is always a multiple of 8 here

  float acc[8][8];
  #pragma unroll
  for (int i = 0; i < 8; ++i)
    #pragma unroll
    for (int j = 0; j < 8; ++j) acc[i][j] = 0.f;

  const float* Aptr = A + (size_t)(bm + ar) * K + ak;
  const float* Bptr = Bm + (size_t)br * N + bn + bc;

  for (int k0 = 0; k0 < K; k0 += 16) {
    float4 a0 = *(const float4*)(Aptr + k0);
    float4 a1 = *(const float4*)(Aptr + k0 + 4);
    float4 b0 = make_float4(0.f,0.f,0.f,0.f), b1 = b0;
    if (bok) {
      b0 = *(const float4*)(Bptr + (size_t)k0 * N);
      b1 = *(const float4*)(Bptr + (size_t)k0 * N + 4);
    }
    __syncthreads();
    As[ak+0][ar] = a0.x; As[ak+1][ar] = a0.y; As[ak+2][ar] = a0.z; As[ak+3][ar] = a0.w;
    As[ak+4][ar] = a1.x; As[ak+5][ar] = a1.y; As[ak+6][ar] = a1.z; As[ak+7][ar] = a1.w;
    *(float4*)&Bs[br][bc]   = b0;
    *(float4*)&Bs[br][bc+4] = b1;
    __syncthreads();
    #pragma unroll
    for (int kk = 0; kk < 16; ++kk) {
      float4 a0r = *(const float4*)&As[kk][ty*8];
      float4 a1r = *(const float4*)&As[kk][ty*8+4];
      float4 b0r = *(const float4*)&Bs[kk][tx*8];
      float4 b1r = *(const float4*)&Bs[kk][tx*8+4];
      float av[8] = {a0r.x,a0r.y,a0r.z,a0r.w,a1r.x,a1r.y,a1r.z,a1r.w};
      float bv[8] = {b0r.x,b0r.y,b0r.z,b0r.w,b1r.x,b1r.y,b1r.z,b1r.w};
      #pragma unroll
      for (int i = 0; i < 8; ++i)
        #pragma unroll
        for (int j = 0; j < 8; ++j)
          acc[i][j] = fmaf(av[i], bv[j], acc[i][j]);
    }
  }
  if (!bok) return;
  #pragma unroll
  for (int i = 0; i < 8; ++i) {
    const size_t m = (size_t)bm + ty*8 + i;
    float outv[8];
    #pragma unroll
    for (int j = 0; j < 8; ++j) {
      float va = acc[i][j];
      const size_t n = (size_t)bn + tx*8 + j;
      if (EPI == 1) va = res[m*N + n] + va + bias[n];
      else if (EPI == 2) va = va / (1.f + __expf(-va));
      else if (EPI == 3) va = res[m*N + n] + va;
      outv[j] = va;
    }
    *(float4*)&C[m*N + bn + tx*8]     = make_float4(outv[0],outv[1],outv[2],outv[3]);
    *(float4*)&C[m*N + bn + tx*8 + 4] = make_float4(outv[4],outv[5],outv[6],outv[7]);
  }
}

// ---------------- attention: one block (512 thr) per (b,h); lane = q-row ----------------
__launch_bounds__(512)
__global__ void attn_kernel(const float* __restrict__ qkv, const float* __restrict__ pos_emb,
                            float* __restrict__ O) {
  __shared__ float Ks[T_ * 32];
  __shared__ float Vs[T_ * 32];
  __shared__ float pe[T_];
  const int bh = blockIdx.x;
  const int b = bh >> 4;
  const int h = bh & 15;
  const int tid = threadIdx.x;
  const size_t base = (size_t)b * T_ * N_QKV;
  const int hoff = h * D_;

  for (int idx = tid; idx < T_ * D_; idx += 512) {
    int s = idx / D_;
    int d = idx - s * D_;
    size_t src = base + (size_t)s * N_QKV + hoff + d;
    Ks[s*32 + d] = qkv[src + C_];
    Vs[s*32 + d] = qkv[src + 2*C_];
  }
  for (int idx = tid; idx < T_ * 3; idx += 512) {
    int s = idx / 3;
    int d = D_ + (idx - s*3);
    Ks[s*32 + d] = 0.f;
    Vs[s*32 + d] = 0.f;
  }
  pe[tid] = pos_emb[(size_t)h * T_ + tid];
  __syncthreads();

  const int t = tid;
  float q[32];
  #pragma unroll
  for (int d = 0; d < D_; ++d) q[d] = qkv[base + (size_t)t * N_QKV + hoff + d];
  q[29] = q[30] = q[31] = 0.f;
  float acc[32];
  #pragma unroll
  for (int d = 0; d < 32; ++d) acc[d] = 0.f;
  float m_u = -INFINITY, l = 0.f;
  const float scale = 0.18569533817705186f;  // 29^-0.5
  const int smax = t | 63;                   // uniform per wave
  for (int s = 0; s <= smax; ++s) {
    const float* kr = &Ks[s*32];
    float c0=0.f,c1=0.f,c2=0.f,c3=0.f;
    #pragma unroll
    for (int j = 0; j < 8; ++j) {
      float4 kv = *(const float4*)(kr + 4*j);
      c0 = fmaf(q[4*j+0], kv.x, c0);
      c1 = fmaf(q[4*j+1], kv.y, c1);
      c2 = fmaf(q[4*j+2], kv.z, c2);
      c3 = fmaf(q[4*j+3], kv.w, c3);
    }
    if (s <= t) {
      float score = ((c0+c1)+(c2+c3) + pe[t-s]) * scale;  // bias added BEFORE scale
      if (score > m_u + 8.f) {   // defer-max rescale (T13)
        float corr = __expf(m_u - score);
        l *= corr;
        #pragma unroll
        for (int d = 0; d < 32; ++d) acc[d] *= corr;
        m_u = score;
      }
      float p = __expf(score - m_u);
      l += p;
      const float* vr = &Vs[s*32];
      #pragma unroll
      for (int j = 0; j < 8; ++j) {
        float4 vv = *(const float4*)(vr + 4*j);
        acc[4*j+0] = fmaf(p, vv.x, acc[4*j+0]);
        acc[4*j+1] = fmaf(p, vv.y, acc[4*j+1]);
        acc[4*j+2] = fmaf(p, vv.z, acc[4*j+2]);
        acc[4*j+3] = fmaf(p, vv.w, acc[4*j+3]);
      }
    }
  }
  const float inv = 1.f / l;
  size_t dst = (size_t)(b * T_ + t) * C_ + hoff;
  #pragma unroll
  for (int d = 0; d < D_; ++d) O[dst + d] = acc[d] * inv;
}

extern "C" void kernel_launch(void* const* d_in, const int* in_sizes, int n_in,
                              void* d_out, int out_size, void* d_ws, size_t ws_size,
                              hipStream_t stream) {
  const float* x       = (const float*)d_in[0];
  // d_in[1] = pos_idx (int64) unused: bias index is just t-s under causal mask
  const float* wq      = (const float*)d_in[2];
  const float* wk      = (const float*)d_in[3];
  const float* wv      = (const float*)d_in[4];
  const float* pos_emb = (const float*)d_in[5];
  const float* w_proj  = (const float*)d_in[6];
  const float* b_proj  = (const float*)d_in[7];
  const float* g1      = (const float*)d_in[8];
  const float* g2      = (const float*)d_in[9];
  const float* w1      = (const float*)d_in[10];
  const float* w2      = (const float*)d_in[11];
  float* out = (float*)d_out;

  float* ws   = (float*)d_ws;
  float* Wqkv = ws;                                  // 464*1392
  float* h1   = Wqkv + (size_t)C_ * N_QKV;           // 8192*464 (reused as h2)
  float* qkv  = h1 + (size_t)BT_ * C_;               // 8192*1392
  float* o    = qkv + (size_t)BT_ * N_QKV;           // 8192*464
  float* ff   = o + (size_t)BT_ * C_;                // 8192*1856
  // total ~139.4 MB of workspace

  prep_wqkv<<<dim3((3*C_*C_ + 255)/256), 256, 0, stream>>>(wq, wk, wv, Wqkv);
  rmsnorm_kernel<<<BT_, 128, 0, stream>>>(x, g1, h1);
  gemm_f32<0><<<dim3(BT_/128, (N_QKV+127)/128), 256, 0, stream>>>(h1, Wqkv, qkv, nullptr, nullptr, BT_, N_QKV, C_);
  attn_kernel<<<B_*H_, 512, 0, stream>>>(qkv, pos_emb, o);
  gemm_f32<1><<<dim3(BT_/128, (C_+127)/128), 256, 0, stream>>>(o, w_proj, out, x, b_proj, BT_, C_, C_);
  rmsnorm_kernel<<<BT_, 128, 0, stream>>>(out, g2, h1);
  gemm_f32<2><<<dim3(BT_/128, (C4_+127)/128), 256, 0, stream>>>(h1, w1, ff, nullptr, nullptr, BT_, C4_, C_);
  gemm_f32<3><<<dim3(BT_/128, (C_+127)/128), 256, 0, stream>>>(ff, w2, out, out, nullptr, BT_, C_, C4_);
}

// Round 2
// 352.884 us; speedup vs baseline: 2.3462x; 2.3462x over previous
//
#include <hip/hip_runtime.h>
#include <math.h>

#define B_ 16
#define T_ 512
#define C_ 464
#define H_ 16
#define D_ 29
#define BT_ 8192
#define NQKV 1392
#define NQKV_P 1408
#define KP 480        // 464 padded to multiple of 32
#define C4 1856       // 4*C (already multiple of 32)
#define C4P 1920      // 1856 padded to multiple of 128
#define NPC 512       // 464 padded to multiple of 128

typedef __attribute__((ext_vector_type(8))) short short8;
typedef __attribute__((ext_vector_type(4))) float f32x4;
typedef __attribute__((ext_vector_type(4))) unsigned short ushort4v;

static __device__ __forceinline__ unsigned short f2bf(float f) {
  union { float f; unsigned u; } v; v.f = f;
  unsigned r = v.u + 0x7FFFu + ((v.u >> 16) & 1u);
  return (unsigned short)(r >> 16);
}

static __device__ __forceinline__ void load_lds16(const void* g, void* l) {
  __builtin_amdgcn_global_load_lds((const __attribute__((address_space(1))) unsigned int*)g,
                                   (__attribute__((address_space(3))) unsigned int*)l,
                                   16, 0, 0);
}

// ---------------- weight prep: (H,C,D)x3 -> bf16 [NQKV_P][KP] transposed ----------------
__global__ void prep_wqkvt(const float* __restrict__ wq, const float* __restrict__ wk,
                           const float* __restrict__ wv, unsigned short* __restrict__ W) {
  int idx = blockIdx.x * 256 + threadIdx.x;
  if (idx >= NQKV_P * KP) return;
  int n = idx / KP, k = idx - n * KP;
  float val = 0.f;
  if (n < NQKV && k < C_) {
    int which = n / C_;
    int hd = n - which * C_;
    int h = hd / D_, d = hd - h * D_;
    const float* s = (which == 0) ? wq : (which == 1) ? wk : wv;
    val = s[((size_t)h * C_ + k) * D_ + d];
  }
  W[idx] = f2bf(val);
}

// generic: f32 [K][N] row-major -> bf16 [Np][Kp] (transposed, zero-padded)
__global__ void prep_wt(const float* __restrict__ src, unsigned short* __restrict__ dst,
                        int N, int K, int Kp, int total) {
  int idx = blockIdx.x * 256 + threadIdx.x;
  if (idx >= total) return;
  int n = idx / Kp, k = idx - n * Kp;
  float val = (k < K && n < N) ? src[(size_t)k * N + n] : 0.f;
  dst[idx] = f2bf(val);
}

// ---------------- rmsnorm: f32 in [8192][464] -> bf16 out [8192][480] ----------------
__launch_bounds__(128)
__global__ void rmsnorm_bf16(const float* __restrict__ X, const float* __restrict__ g,
                             unsigned short* __restrict__ Y) {
  const int row = blockIdx.x;
  const int tid = threadIdx.x;
  __shared__ float red[2];
  float4 v = make_float4(0.f, 0.f, 0.f, 0.f);
  float ss = 0.f;
  if (tid < C_ / 4) {
    v = ((const float4*)(X + (size_t)row * C_))[tid];
    ss = v.x * v.x + v.y * v.y + v.z * v.z + v.w * v.w;
  }
  #pragma unroll
  for (int off = 32; off > 0; off >>= 1) ss += __shfl_xor(ss, off);
  if ((tid & 63) == 0) red[tid >> 6] = ss;
  __syncthreads();
  float rs = rsqrtf((red[0] + red[1]) * (1.f / C_) + 1e-5f);
  if (tid < C_ / 4) {
    float4 gg = ((const float4*)g)[tid];
    ushort4v y;
    y.x = f2bf(v.x * rs * gg.x); y.y = f2bf(v.y * rs * gg.y);
    y.z = f2bf(v.z * rs * gg.z); y.w = f2bf(v.w * rs * gg.w);
    *(ushort4v*)(Y + (size_t)row * KP + tid * 4) = y;
  } else if (tid < 120) {
    ushort4v z = {0, 0, 0, 0};
    *(ushort4v*)(Y + (size_t)row * KP + tid * 4) = z;
  }
}

// ---------------- bf16 MFMA GEMM: C[M=8192][N] = A[.][K] * Bt[n][K]^T ----------------
// 128x128 tile, 4 waves (2x2), 4x4 16x16x32 fragments per wave, BK=32.
// LDS granule swizzle: phys_granule = logical ^ ((row>>1)&3), applied on the
// pre-swizzled global source (linear global_load_lds dest) and on ds_read.
// EPI: 0 = f32 out; 1 = res + bias -> f32; 2 = silu -> bf16; 3 = res -> f32
template<int EPI>
__launch_bounds__(256)
__global__ void gemm_mfma(const unsigned short* __restrict__ A,
                          const unsigned short* __restrict__ Bt,
                          float* __restrict__ Cf, unsigned short* __restrict__ Cb,
                          const float* __restrict__ res, const float* __restrict__ bias,
                          int N, int K, int ldc) {
  __shared__ __align__(16) unsigned short As[4096];
  __shared__ __align__(16) unsigned short Bs[4096];
  const int tid = threadIdx.x;
  const int w = tid >> 6, lane = tid & 63;
  const int bm = blockIdx.x * 128, bn = blockIdx.y * 128;

  // staging: wave w issues 2 calls each for A and B; call j fills LDS ushorts
  // [w*1024 + j*512, +512). lane's chunk ci=(w*2+j)*64+lane -> row=ci>>2,
  // phys granule=ci&3, logical granule g = (ci&3) ^ ((row>>1)&3).
  const int q = lane >> 2;
  const int g = (lane & 3) ^ ((lane >> 3) & 3);
  const int r0 = w * 32 + q;
  const unsigned short* ga0 = A + (size_t)(bm + r0) * K + g * 8;
  const unsigned short* ga1 = ga0 + (size_t)16 * K;
  const unsigned short* gb0 = Bt + (size_t)(bn + r0) * K + g * 8;
  const unsigned short* gb1 = gb0 + (size_t)16 * K;
  unsigned short* la0 = As + w * 1024;
  unsigned short* lb0 = Bs + w * 1024;

  // read side: lane (h=l>>4, fr=l&15) reads row base+fr, logical granule h,
  // phys granule h ^ ((fr>>1)&3)
  const int fr = lane & 15;
  const int gp = (lane >> 4) ^ ((lane >> 1) & 3);
  const int wr = (w >> 1) * 64, wc = (w & 1) * 64;
  int aoff[4], boff[4];
  #pragma unroll
  for (int m = 0; m < 4; ++m) aoff[m] = (wr + m * 16 + fr) * 32 + gp * 8;
  #pragma unroll
  for (int n = 0; n < 4; ++n) boff[n] = (wc + n * 16 + fr) * 32 + gp * 8;

  f32x4 acc[4][4];
  #pragma unroll
  for (int m = 0; m < 4; ++m)
    #pragma unroll
    for (int n = 0; n < 4; ++n) acc[m][n] = (f32x4){0.f, 0.f, 0.f, 0.f};

  for (int k0 = 0; k0 < K; k0 += 32) {
    __syncthreads();
    load_lds16(ga0 + k0, la0);
    load_lds16(ga1 + k0, la0 + 512);
    load_lds16(gb0 + k0, lb0);
    load_lds16(gb1 + k0, lb0 + 512);
    __syncthreads();
    short8 af[4], bf[4];
    #pragma unroll
    for (int m = 0; m < 4; ++m) af[m] = *(const short8*)(As + aoff[m]);
    #pragma unroll
    for (int n = 0; n < 4; ++n) bf[n] = *(const short8*)(Bs + boff[n]);
    #pragma unroll
    for (int m = 0; m < 4; ++m)
      #pragma unroll
      for (int n = 0; n < 4; ++n)
        acc[m][n] = __builtin_amdgcn_mfma_f32_16x16x32_bf16(af[m], bf[n], acc[m][n], 0, 0, 0);
  }

  // epilogue: C/D layout col=lane&15, row=(lane>>4)*4+reg
  const int crow0 = bm + wr + (lane >> 4) * 4;
  const int ccol0 = bn + wc + fr;
  #pragma unroll
  for (int n = 0; n < 4; ++n) {
    const int col = ccol0 + n * 16;
    if (col >= N) continue;
    #pragma unroll
    for (int m = 0; m < 4; ++m) {
      #pragma unroll
      for (int r = 0; r < 4; ++r) {
        const int row = crow0 + m * 16 + r;
        const size_t o = (size_t)row * ldc + col;
        float v = acc[m][n][r];
        if (EPI == 0) Cf[o] = v;
        else if (EPI == 1) Cf[o] = res[o] + v + bias[col];
        else if (EPI == 2) Cb[o] = f2bf(v / (1.f + __expf(-v)));
        else Cf[o] = res[o] + v;
      }
    }
  }
}

// ---------------- attention: one block (512 thr) per (b,h); lane = q-row ----------------
__launch_bounds__(512)
__global__ void attn_kernel(const float* __restrict__ qkv, const float* __restrict__ pos_emb,
                            unsigned short* __restrict__ Ob) {
  __shared__ float Ks[T_ * 32];
  __shared__ float Vs[T_ * 32];
  __shared__ float pe[T_];
  const int bh = blockIdx.x;
  const int b = bh >> 4;
  const int h = bh & 15;
  const int tid = threadIdx.x;
  const size_t base = (size_t)b * T_ * NQKV;
  const int hoff = h * D_;

  for (int idx = tid; idx < T_ * D_; idx += 512) {
    int s = idx / D_;
    int d = idx - s * D_;
    size_t src = base + (size_t)s * NQKV + hoff + d;
    Ks[s * 32 + d] = qkv[src + C_];
    Vs[s * 32 + d] = qkv[src + 2 * C_];
  }
  for (int idx = tid; idx < T_ * 3; idx += 512) {
    int s = idx / 3;
    int d = D_ + (idx - s * 3);
    Ks[s * 32 + d] = 0.f;
    Vs[s * 32 + d] = 0.f;
  }
  pe[tid] = pos_emb[(size_t)h * T_ + tid];
  __syncthreads();

  const int t = tid;
  float qv[32];
  #pragma unroll
  for (int d = 0; d < D_; ++d) qv[d] = qkv[base + (size_t)t * NQKV + hoff + d];
  qv[29] = qv[30] = qv[31] = 0.f;
  float acc[32];
  #pragma unroll
  for (int d = 0; d < 32; ++d) acc[d] = 0.f;
  float m_u = -INFINITY, l = 0.f;
  const float scale = 0.18569533817705186f;  // 29^-0.5
  const int smax = t | 63;                   // uniform per wave
  for (int s = 0; s <= smax; ++s) {
    const float* kr = &Ks[s * 32];
    float c0 = 0.f, c1 = 0.f, c2 = 0.f, c3 = 0.f;
    #pragma unroll
    for (int j = 0; j < 8; ++j) {
      float4 kv = *(const float4*)(kr + 4 * j);
      c0 = fmaf(qv[4 * j + 0], kv.x, c0);
      c1 = fmaf(qv[4 * j + 1], kv.y, c1);
      c2 = fmaf(qv[4 * j + 2], kv.z, c2);
      c3 = fmaf(qv[4 * j + 3], kv.w, c3);
    }
    if (s <= t) {
      float score = ((c0 + c1) + (c2 + c3) + pe[t - s]) * scale;  // bias BEFORE scale
      if (score > m_u + 8.f) {   // defer-max rescale (T13)
        float corr = __expf(m_u - score);
        l *= corr;
        #pragma unroll
        for (int d = 0; d < 32; ++d) acc[d] *= corr;
        m_u = score;
      }
      float p = __expf(score - m_u);
      l += p;
      const float* vr = &Vs[s * 32];
      #pragma unroll
      for (int j = 0; j < 8; ++j) {
        float4 vv = *(const float4*)(vr + 4 * j);
        acc[4 * j + 0] = fmaf(p, vv.x, acc[4 * j + 0]);
        acc[4 * j + 1] = fmaf(p, vv.y, acc[4 * j + 1]);
        acc[4 * j + 2] = fmaf(p, vv.z, acc[4 * j + 2]);
        acc[4 * j + 3] = fmaf(p, vv.w, acc[4 * j + 3]);
      }
    }
  }
  const float inv = 1.f / l;
  unsigned short* orow = Ob + (size_t)(b * T_ + t) * KP + hoff;
  #pragma unroll
  for (int d = 0; d < D_; ++d) orow[d] = f2bf(acc[d] * inv);
  if (h == 15) {
    unsigned short* prow = Ob + (size_t)(b * T_ + t) * KP + 464;
    #pragma unroll
    for (int d = 0; d < 16; ++d) prow[d] = 0;
  }
}

extern "C" void kernel_launch(void* const* d_in, const int* in_sizes, int n_in,
                              void* d_out, int out_size, void* d_ws, size_t ws_size,
                              hipStream_t stream) {
  const float* x       = (const float*)d_in[0];
  // d_in[1] = pos_idx (int64) unused: bias index is t-s under the causal mask
  const float* wq      = (const float*)d_in[2];
  const float* wk      = (const float*)d_in[3];
  const float* wv      = (const float*)d_in[4];
  const float* pos_emb = (const float*)d_in[5];
  const float* w_proj  = (const float*)d_in[6];
  const float* b_proj  = (const float*)d_in[7];
  const float* g1      = (const float*)d_in[8];
  const float* g2      = (const float*)d_in[9];
  const float* w1      = (const float*)d_in[10];
  const float* w2      = (const float*)d_in[11];
  float* out = (float*)d_out;

  char* cur = (char*)d_ws;
  auto alloc = [&](size_t bytes) { char* p = cur; cur += (bytes + 255) & ~(size_t)255; return p; };
  unsigned short* Wqkvt = (unsigned short*)alloc((size_t)NQKV_P * KP * 2);
  unsigned short* Wprt  = (unsigned short*)alloc((size_t)NPC * KP * 2);
  unsigned short* W1t   = (unsigned short*)alloc((size_t)C4P * KP * 2);
  unsigned short* W2t   = (unsigned short*)alloc((size_t)NPC * C4 * 2);
  unsigned short* h1b   = (unsigned short*)alloc((size_t)BT_ * KP * 2);   // reused for h2
  unsigned short* ob    = (unsigned short*)alloc((size_t)BT_ * KP * 2);
  unsigned short* ffb   = (unsigned short*)alloc((size_t)BT_ * C4 * 2);
  float*          qkv   = (float*)alloc((size_t)BT_ * NQKV * 4);

  prep_wqkvt<<<(NQKV_P * KP + 255) / 256, 256, 0, stream>>>(wq, wk, wv, Wqkvt);
  prep_wt<<<(NPC * KP + 255) / 256, 256, 0, stream>>>(w_proj, Wprt, C_, C_, KP, NPC * KP);
  prep_wt<<<(C4P * KP + 255) / 256, 256, 0, stream>>>(w1, W1t, C4, C_, KP, C4P * KP);
  prep_wt<<<(NPC * C4 + 255) / 256, 256, 0, stream>>>(w2, W2t, C_, C4, C4, NPC * C4);

  rmsnorm_bf16<<<BT_, 128, 0, stream>>>(x, g1, h1b);
  gemm_mfma<0><<<dim3(BT_ / 128, NQKV_P / 128), 256, 0, stream>>>(
      h1b, Wqkvt, qkv, nullptr, nullptr, nullptr, NQKV, KP, NQKV);
  attn_kernel<<<B_ * H_, 512, 0, stream>>>(qkv, pos_emb, ob);
  gemm_mfma<1><<<dim3(BT_ / 128, NPC / 128), 256, 0, stream>>>(
      ob, Wprt, out, nullptr, x, b_proj, C_, KP, C_);
  rmsnorm_bf16<<<BT_, 128, 0, stream>>>(out, g2, h1b);
  gemm_mfma<2><<<dim3(BT_ / 128, C4P / 128), 256, 0, stream>>>(
      h1b, W1t, nullptr, ffb, nullptr, nullptr, C4, KP, C4);
  gemm_mfma<3><<<dim3(BT_ / 128, NPC / 128), 256, 0, stream>>>(
      ffb, W2t, out, nullptr, out, nullptr, C_, C4, C_);
}

// Round 4
// 219.683 us; speedup vs baseline: 3.7687x; 1.6063x over previous
//
#include <hip/hip_runtime.h>
#include <math.h>

#define B_ 16
#define T_ 512
#define C_ 464
#define H_ 16
#define D_ 29
#define BT_ 8192
#define NQKV 1392
#define NQKV_P 1408
#define KP 480        // 464 padded to multiple of 32
#define C4 1856       // 4*C
#define C4P 1920
#define NPC 512

typedef __attribute__((ext_vector_type(8))) short short8;
typedef __attribute__((ext_vector_type(4))) float f32x4;
typedef __attribute__((ext_vector_type(16))) float f32x16;
typedef __attribute__((ext_vector_type(4))) unsigned short ushort4v;

static __device__ __forceinline__ unsigned short f2bf(float f) {
  union { float f; unsigned u; } v; v.f = f;
  unsigned r = v.u + 0x7FFFu + ((v.u >> 16) & 1u);
  return (unsigned short)(r >> 16);
}

static __device__ __forceinline__ void load_lds16(const void* g, void* l) {
  __builtin_amdgcn_global_load_lds((const __attribute__((address_space(1))) unsigned int*)g,
                                   (__attribute__((address_space(3))) unsigned int*)l,
                                   16, 0, 0);
}

#define CVTPK(dst, a, b) asm("v_cvt_pk_bf16_f32 %0, %1, %2" : "=v"(dst) : "v"(a), "v"(b))

// ---------------- weight prep ----------------
__global__ void prep_wqkvt(const float* __restrict__ wq, const float* __restrict__ wk,
                           const float* __restrict__ wv, unsigned short* __restrict__ W) {
  int idx = blockIdx.x * 256 + threadIdx.x;
  if (idx >= NQKV_P * KP) return;
  int n = idx / KP, k = idx - n * KP;
  float val = 0.f;
  if (n < NQKV && k < C_) {
    int which = n / C_;
    int hd = n - which * C_;
    int h = hd / D_, d = hd - h * D_;
    const float* s = (which == 0) ? wq : (which == 1) ? wk : wv;
    val = s[((size_t)h * C_ + k) * D_ + d];
  }
  W[idx] = f2bf(val);
}

__global__ void prep_wt(const float* __restrict__ src, unsigned short* __restrict__ dst,
                        int N, int K, int Kp, int total) {
  int idx = blockIdx.x * 256 + threadIdx.x;
  if (idx >= total) return;
  int n = idx / Kp, k = idx - n * Kp;
  float val = (k < K && n < N) ? src[(size_t)k * N + n] : 0.f;
  dst[idx] = f2bf(val);
}

// ---------------- rmsnorm: f32 [8192][464] -> bf16 [8192][480] ----------------
__launch_bounds__(128)
__global__ void rmsnorm_bf16(const float* __restrict__ X, const float* __restrict__ g,
                             unsigned short* __restrict__ Y) {
  const int row = blockIdx.x;
  const int tid = threadIdx.x;
  __shared__ float red[2];
  float4 v = make_float4(0.f, 0.f, 0.f, 0.f);
  float ss = 0.f;
  if (tid < C_ / 4) {
    v = ((const float4*)(X + (size_t)row * C_))[tid];
    ss = v.x * v.x + v.y * v.y + v.z * v.z + v.w * v.w;
  }
  #pragma unroll
  for (int off = 32; off > 0; off >>= 1) ss += __shfl_xor(ss, off);
  if ((tid & 63) == 0) red[tid >> 6] = ss;
  __syncthreads();
  float rs = rsqrtf((red[0] + red[1]) * (1.f / C_) + 1e-5f);
  if (tid < C_ / 4) {
    float4 gg = ((const float4*)g)[tid];
    ushort4v y;
    y.x = f2bf(v.x * rs * gg.x); y.y = f2bf(v.y * rs * gg.y);
    y.z = f2bf(v.z * rs * gg.z); y.w = f2bf(v.w * rs * gg.w);
    *(ushort4v*)(Y + (size_t)row * KP + tid * 4) = y;
  } else if (tid < 120) {
    ushort4v z = {0, 0, 0, 0};
    *(ushort4v*)(Y + (size_t)row * KP + tid * 4) = z;
  }
}

// ---------------- bf16 MFMA GEMM (128x128 tile, 4 waves, 16x16x32) ----------------
// EPI: 1 = res+bias->f32; 2 = silu->bf16; 3 = res->f32; 4 = QKV scatter (swizzle-baked)
template<int EPI>
__launch_bounds__(256)
__global__ void gemm_mfma(const unsigned short* __restrict__ A,
                          const unsigned short* __restrict__ Bt,
                          float* __restrict__ Cf, unsigned short* __restrict__ Cb,
                          const float* __restrict__ res, const float* __restrict__ bias,
                          int N, int K, int ldc,
                          unsigned short* __restrict__ Kb2, unsigned short* __restrict__ Vt2) {
  __shared__ __align__(16) unsigned short As[4096];
  __shared__ __align__(16) unsigned short Bs[4096];
  const int tid = threadIdx.x;
  const int w = tid >> 6, lane = tid & 63;
  const int bm = blockIdx.x * 128, bn = blockIdx.y * 128;

  const int q = lane >> 2;
  const int g = (lane & 3) ^ ((lane >> 3) & 3);
  const int r0 = w * 32 + q;
  const unsigned short* ga0 = A + (size_t)(bm + r0) * K + g * 8;
  const unsigned short* ga1 = ga0 + (size_t)16 * K;
  const unsigned short* gb0 = Bt + (size_t)(bn + r0) * K + g * 8;
  const unsigned short* gb1 = gb0 + (size_t)16 * K;
  unsigned short* la0 = As + w * 1024;
  unsigned short* lb0 = Bs + w * 1024;

  const int fr = lane & 15;
  const int gp = (lane >> 4) ^ ((lane >> 1) & 3);
  const int wr = (w >> 1) * 64, wc = (w & 1) * 64;
  int aoff[4], boff[4];
  #pragma unroll
  for (int m = 0; m < 4; ++m) aoff[m] = (wr + m * 16 + fr) * 32 + gp * 8;
  #pragma unroll
  for (int n = 0; n < 4; ++n) boff[n] = (wc + n * 16 + fr) * 32 + gp * 8;

  f32x4 acc[4][4];
  #pragma unroll
  for (int m = 0; m < 4; ++m)
    #pragma unroll
    for (int n = 0; n < 4; ++n) acc[m][n] = (f32x4){0.f, 0.f, 0.f, 0.f};

  for (int k0 = 0; k0 < K; k0 += 32) {
    __syncthreads();
    load_lds16(ga0 + k0, la0);
    load_lds16(ga1 + k0, la0 + 512);
    load_lds16(gb0 + k0, lb0);
    load_lds16(gb1 + k0, lb0 + 512);
    __syncthreads();
    short8 af[4], bf[4];
    #pragma unroll
    for (int m = 0; m < 4; ++m) af[m] = *(const short8*)(As + aoff[m]);
    #pragma unroll
    for (int n = 0; n < 4; ++n) bf[n] = *(const short8*)(Bs + boff[n]);
    #pragma unroll
    for (int m = 0; m < 4; ++m)
      #pragma unroll
      for (int n = 0; n < 4; ++n)
        acc[m][n] = __builtin_amdgcn_mfma_f32_16x16x32_bf16(af[m], bf[n], acc[m][n], 0, 0, 0);
  }

  const int crow0 = bm + wr + (lane >> 4) * 4;
  const int ccol0 = bn + wc + fr;
  #pragma unroll
  for (int n = 0; n < 4; ++n) {
    const int col = ccol0 + n * 16;
    if (col >= N) continue;
    #pragma unroll
    for (int m = 0; m < 4; ++m) {
      #pragma unroll
      for (int r = 0; r < 4; ++r) {
        const int row = crow0 + m * 16 + r;
        const size_t o = (size_t)row * ldc + col;
        float v = acc[m][n][r];
        if (EPI == 1) Cf[o] = res[o] + v + bias[col];
        else if (EPI == 2) Cb[o] = f2bf(v / (1.f + __expf(-v)));
        else if (EPI == 3) Cf[o] = res[o] + v;
        else if (EPI == 4) {
          // scatter to Qb(Cb)/Kb2/Vt2 with swizzles baked
          int which = col / C_;
          int hd = col - which * C_;
          int hh = hd / D_;
          int d = hd - hh * D_;
          unsigned short bv = f2bf(v);
          if (which < 2) {
            unsigned short* dst = (which == 0) ? Cb : Kb2;
            int pg = (d >> 3) ^ ((row >> 1) & 3);
            size_t base = (size_t)row * 512 + hh * 32;
            dst[base + pg * 8 + (d & 7)] = bv;
            if (d == 28) {            // zero the 3 pad slots (same granule)
              dst[base + pg * 8 + 5] = 0;
              dst[base + pg * 8 + 6] = 0;
              dst[base + pg * 8 + 7] = 0;
            }
          } else {
            int bb = row >> 9, tt = row & 511;
            int pg = ((tt >> 3) & 7) ^ (d & 7);
            Vt2[((size_t)((bb * 16 + hh) * 32 + d)) * 512 + (tt & ~63) + pg * 8 + (tt & 7)] = bv;
          }
        }
      }
    }
  }
}

// ---------------- MFMA flash attention ----------------
// block = (b, h, 128-q tile); 4 waves, wave = 32-q strip; s-tiles of 64, dbuf.
// S^T = mfma32x32x16(K, Q^T): lane owns q = lane&31 -> per-lane online softmax.
// O^T = mfma(V^T, P^T): P^T frag built in-register (cvt_pk + permlane32_swap).
__launch_bounds__(256)
__global__ void attn_mfma(const unsigned short* __restrict__ Qb,
                          const unsigned short* __restrict__ Kb,
                          const unsigned short* __restrict__ Vt,
                          const float* __restrict__ pos_emb,
                          unsigned short* __restrict__ Ob) {
  __shared__ __align__(16) unsigned short Qs[4096];     // [128][32]
  __shared__ __align__(16) unsigned short Ks[2][2048];  // [64][32]
  __shared__ __align__(16) unsigned short Vs[2][2048];  // [32][64]
  __shared__ __align__(16) float pes[512];
  const int blk = blockIdx.x;
  const int qt = blk & 3, bh = blk >> 2;
  const int b = bh >> 4, h = bh & 15;
  const int tid = threadIdx.x;
  const int w = tid >> 6, lane = tid & 63;
  const int l31 = lane & 31, hi = lane >> 5;
  const int qb = qt * 128;

  const char* gq = (const char*)Qb + ((size_t)(b * 512 + qb) * 512 + h * 32) * 2;
  const char* gk = (const char*)Kb + ((size_t)(b * 512) * 512 + h * 32) * 2;
  const char* gv = (const char*)Vt + ((size_t)(bh * 32) * 512) * 2;

  // prologue staging: Q (8KB), pe (2KB), tile0 K/V
  load_lds16(gq + (size_t)(tid >> 2) * 1024 + (tid & 3) * 16, (char*)Qs + w * 1024);
  load_lds16(gq + (size_t)((tid >> 2) + 64) * 1024 + (tid & 3) * 16, (char*)Qs + 4096 + w * 1024);
  if (tid < 128)
    load_lds16((const char*)pos_emb + h * 2048 + tid * 16, (char*)pes + w * 1024);
  load_lds16(gk + (size_t)(tid >> 2) * 1024 + (tid & 3) * 16, (char*)Ks[0] + w * 1024);
  load_lds16(gv + (size_t)(tid >> 3) * 1024 + (tid & 7) * 16, (char*)Vs[0] + w * 1024);
  __syncthreads();

  // hoist Q fragments (B-slot: lane holds Q[q=lane&31][d=hi*8+j+16kc])
  const int qrow = w * 32 + l31;
  short8 qf[2];
  #pragma unroll
  for (int kc = 0; kc < 2; ++kc) {
    int pg = (hi + 2 * kc) ^ ((qrow >> 1) & 3);
    qf[kc] = *(const short8*)(Qs + qrow * 32 + pg * 8);
  }

  const int q_min = qb + w * 32;
  const int t = q_min + l31;
  const int s_w = (q_min >> 6) + 1;          // tiles this wave computes
  const int nt = ((qb + 96) >> 6) + 1;       // tiles staged (max over waves)
  const float scale2 = 0.18569533817705186f * 1.4426950408889634f;  // 29^-.5 * log2e
  f32x16 oacc;
  #pragma unroll
  for (int r = 0; r < 16; ++r) oacc[r] = 0.f;
  float m_run = -1e30f, l_run = 0.f;

  for (int si = 0; si < nt; ++si) {
    const int c = si & 1;
    if (si + 1 < nt) {  // prefetch next tile into buf c^1
      const int sb = (si + 1) * 64;
      load_lds16(gk + (size_t)(sb + (tid >> 2)) * 1024 + (tid & 3) * 16, (char*)Ks[c ^ 1] + w * 1024);
      load_lds16(gv + (size_t)(tid >> 3) * 1024 + sb * 2 + (tid & 7) * 16, (char*)Vs[c ^ 1] + w * 1024);
    }
    if (si < s_w) {
      const int sbase = si * 64;
      f32x16 sc[2];
      #pragma unroll
      for (int sf = 0; sf < 2; ++sf) {
        int srow = 32 * sf + l31;
        f32x16 a;
        #pragma unroll
        for (int r = 0; r < 16; ++r) a[r] = 0.f;
        #pragma unroll
        for (int kc = 0; kc < 2; ++kc) {
          int pg = (hi + 2 * kc) ^ ((srow >> 1) & 3);
          short8 kf = *(const short8*)(&Ks[c][0] + srow * 32 + pg * 8);
          a = __builtin_amdgcn_mfma_f32_32x32x16_bf16(kf, qf[kc], a, 0, 0, 0);
        }
        sc[sf] = a;
      }
      const bool edge = (si == s_w - 1);
      float mt = -1e30f;
      #pragma unroll
      for (int sf = 0; sf < 2; ++sf)
        #pragma unroll
        for (int r = 0; r < 16; ++r) {
          int s_abs = sbase + 32 * sf + ((r & 3) + 8 * (r >> 2)) + 4 * hi;
          int idx = t - s_abs;
          float v;
          if (edge) {
            float bias = pes[idx < 0 ? 0 : idx];
            v = (sc[sf][r] + bias) * scale2;
            if (idx < 0) v = -1e30f;
          } else {
            v = (sc[sf][r] + pes[idx]) * scale2;
          }
          sc[sf][r] = v;
          mt = fmaxf(mt, v);
        }
      mt = fmaxf(mt, __shfl_xor(mt, 32));
      if (mt > m_run + 11.5f) {   // defer-max (T13), exp2 space
        float corr = exp2f(m_run - mt);
        l_run *= corr;
        #pragma unroll
        for (int r = 0; r < 16; ++r) oacc[r] *= corr;
        m_run = mt;
      }
      float ls = 0.f;
      #pragma unroll
      for (int sf = 0; sf < 2; ++sf)
        #pragma unroll
        for (int r = 0; r < 16; ++r) {
          float p = exp2f(sc[sf][r] - m_run);
          sc[sf][r] = p;
          ls += p;
        }
      l_run += ls + __shfl_xor(ls, 32);
      // P^T fragments: per 16-s chunk kc: 4 bf16x2 words via cvt_pk + permlane32_swap.
      // permlane32_swap(vdst,vsrc): new vdst=[vdst_lo|vsrc_lo], new vsrc=[vdst_hi|vsrc_hi]
      unsigned pw[4][4];
      #pragma unroll
      for (int sf = 0; sf < 2; ++sf)
        #pragma unroll
        for (int kk = 0; kk < 2; ++kk) {
          const int kc = sf * 2 + kk;
          const int rb = kk * 8;
          unsigned pk01, pk23, pk45, pk67;
          CVTPK(pk01, sc[sf][rb + 0], sc[sf][rb + 1]);
          CVTPK(pk23, sc[sf][rb + 2], sc[sf][rb + 3]);
          CVTPK(pk45, sc[sf][rb + 4], sc[sf][rb + 5]);
          CVTPK(pk67, sc[sf][rb + 6], sc[sf][rb + 7]);
          asm volatile("v_permlane32_swap_b32 %0, %1" : "+v"(pk01), "+v"(pk45));
          asm volatile("v_permlane32_swap_b32 %0, %1" : "+v"(pk23), "+v"(pk67));
          pw[kc][0] = pk01; pw[kc][1] = pk23; pw[kc][2] = pk45; pw[kc][3] = pk67;
        }
      // PV: O^T += V^T · P^T
      #pragma unroll
      for (int kc = 0; kc < 4; ++kc) {
        int pg = (2 * kc + hi) ^ (l31 & 7);
        short8 vf = *(const short8*)(&Vs[c][0] + l31 * 64 + pg * 8);
        union { unsigned u[4]; short8 s8; } pu;
        pu.u[0] = pw[kc][0]; pu.u[1] = pw[kc][1]; pu.u[2] = pw[kc][2]; pu.u[3] = pw[kc][3];
        oacc = __builtin_amdgcn_mfma_f32_32x32x16_bf16(vf, pu.s8, oacc, 0, 0, 0);
      }
    }
    __syncthreads();
  }

  const float inv = 1.f / l_run;
  #pragma unroll
  for (int r = 0; r < 16; ++r) {
    int d = (r & 3) + 8 * (r >> 2) + 4 * hi;
    if (d < D_)
      Ob[(size_t)(b * 512 + t) * KP + h * D_ + d] = f2bf(oacc[r] * inv);
  }
  if (h == 15 && tid < 128) {  // zero ob pad cols 464..479 (NaN safety)
    char* p = (char*)(Ob + (size_t)(b * 512 + qb + tid) * KP + C_);
    *(uint4*)p = make_uint4(0, 0, 0, 0);
    *(uint4*)(p + 16) = make_uint4(0, 0, 0, 0);
  }
}

extern "C" void kernel_launch(void* const* d_in, const int* in_sizes, int n_in,
                              void* d_out, int out_size, void* d_ws, size_t ws_size,
                              hipStream_t stream) {
  const float* x       = (const float*)d_in[0];
  const float* wq      = (const float*)d_in[2];
  const float* wk      = (const float*)d_in[3];
  const float* wv      = (const float*)d_in[4];
  const float* pos_emb = (const float*)d_in[5];
  const float* w_proj  = (const float*)d_in[6];
  const float* b_proj  = (const float*)d_in[7];
  const float* g1      = (const float*)d_in[8];
  const float* g2      = (const float*)d_in[9];
  const float* w1      = (const float*)d_in[10];
  const float* w2      = (const float*)d_in[11];
  float* out = (float*)d_out;

  char* cur = (char*)d_ws;
  auto alloc = [&](size_t bytes) { char* p = cur; cur += (bytes + 255) & ~(size_t)255; return p; };
  unsigned short* Wqkvt = (unsigned short*)alloc((size_t)NQKV_P * KP * 2);
  unsigned short* Wprt  = (unsigned short*)alloc((size_t)NPC * KP * 2);
  unsigned short* W1t   = (unsigned short*)alloc((size_t)C4P * KP * 2);
  unsigned short* W2t   = (unsigned short*)alloc((size_t)NPC * C4 * 2);
  unsigned short* h1b   = (unsigned short*)alloc((size_t)BT_ * KP * 2);
  unsigned short* ob    = (unsigned short*)alloc((size_t)BT_ * KP * 2);
  unsigned short* ffb   = (unsigned short*)alloc((size_t)BT_ * C4 * 2);
  unsigned short* Qbuf  = (unsigned short*)alloc((size_t)BT_ * 512 * 2);
  unsigned short* Kbuf  = (unsigned short*)alloc((size_t)BT_ * 512 * 2);
  unsigned short* Vtb   = (unsigned short*)alloc((size_t)BT_ * 512 * 2);

  prep_wqkvt<<<(NQKV_P * KP + 255) / 256, 256, 0, stream>>>(wq, wk, wv, Wqkvt);
  prep_wt<<<(NPC * KP + 255) / 256, 256, 0, stream>>>(w_proj, Wprt, C_, C_, KP, NPC * KP);
  prep_wt<<<(C4P * KP + 255) / 256, 256, 0, stream>>>(w1, W1t, C4, C_, KP, C4P * KP);
  prep_wt<<<(NPC * C4 + 255) / 256, 256, 0, stream>>>(w2, W2t, C_, C4, C4, NPC * C4);

  rmsnorm_bf16<<<BT_, 128, 0, stream>>>(x, g1, h1b);
  gemm_mfma<4><<<dim3(BT_ / 128, NQKV_P / 128), 256, 0, stream>>>(
      h1b, Wqkvt, nullptr, Qbuf, nullptr, nullptr, NQKV, KP, 0, Kbuf, Vtb);
  attn_mfma<<<B_ * H_ * 4, 256, 0, stream>>>(Qbuf, Kbuf, Vtb, pos_emb, ob);
  gemm_mfma<1><<<dim3(BT_ / 128, NPC / 128), 256, 0, stream>>>(
      ob, Wprt, out, nullptr, x, b_proj, C_, KP, C_, nullptr, nullptr);
  rmsnorm_bf16<<<BT_, 128, 0, stream>>>(out, g2, h1b);
  gemm_mfma<2><<<dim3(BT_ / 128, C4P / 128), 256, 0, stream>>>(
      h1b, W1t, nullptr, ffb, nullptr, nullptr, C4, KP, C4, nullptr, nullptr);
  gemm_mfma<3><<<dim3(BT_ / 128, NPC / 128), 256, 0, stream>>>(
      ffb, W2t, out, nullptr, out, nullptr, C_, C4, C_, nullptr, nullptr);
}

// Round 5
// 195.244 us; speedup vs baseline: 4.2405x; 1.1252x over previous
//
#include <hip/hip_runtime.h>
#include <math.h>

#define B_ 16
#define T_ 512
#define C_ 464
#define H_ 16
#define D_ 29
#define BT_ 8192
#define NQKV 1392
#define NQKV_P 1408
#define KP 480        // 464 padded to multiple of 32
#define C4 1856       // 4*C
#define C4P 1920
#define NPC 512

typedef __attribute__((ext_vector_type(8))) short short8;
typedef __attribute__((ext_vector_type(4))) float f32x4;
typedef __attribute__((ext_vector_type(16))) float f32x16;
typedef __attribute__((ext_vector_type(4))) unsigned short ushort4v;

static __device__ __forceinline__ unsigned short f2bf(float f) {
  union { float f; unsigned u; } v; v.f = f;
  unsigned r = v.u + 0x7FFFu + ((v.u >> 16) & 1u);
  return (unsigned short)(r >> 16);
}

static __device__ __forceinline__ void load_lds16(const void* g, void* l) {
  __builtin_amdgcn_global_load_lds((const __attribute__((address_space(1))) unsigned int*)g,
                                   (__attribute__((address_space(3))) unsigned int*)l,
                                   16, 0, 0);
}

#define CVTPK(dst, a, b) asm("v_cvt_pk_bf16_f32 %0, %1, %2" : "=v"(dst) : "v"(a), "v"(b))

// ---------------- weight prep ----------------
__global__ void prep_wqkvt(const float* __restrict__ wq, const float* __restrict__ wk,
                           const float* __restrict__ wv, unsigned short* __restrict__ W) {
  int idx = blockIdx.x * 256 + threadIdx.x;
  if (idx >= NQKV_P * KP) return;
  int n = idx / KP, k = idx - n * KP;
  float val = 0.f;
  if (n < NQKV && k < C_) {
    int which = n / C_;
    int hd = n - which * C_;
    int h = hd / D_, d = hd - h * D_;
    const float* s = (which == 0) ? wq : (which == 1) ? wk : wv;
    val = s[((size_t)h * C_ + k) * D_ + d];
  }
  W[idx] = f2bf(val);
}

__global__ void prep_wt(const float* __restrict__ src, unsigned short* __restrict__ dst,
                        int N, int K, int Kp, int total) {
  int idx = blockIdx.x * 256 + threadIdx.x;
  if (idx >= total) return;
  int n = idx / Kp, k = idx - n * Kp;
  float val = (k < K && n < N) ? src[(size_t)k * N + n] : 0.f;
  dst[idx] = f2bf(val);
}

// ---------------- rmsnorm: f32 [8192][464] -> bf16 [8192][480] ----------------
__launch_bounds__(128)
__global__ void rmsnorm_bf16(const float* __restrict__ X, const float* __restrict__ g,
                             unsigned short* __restrict__ Y) {
  const int row = blockIdx.x;
  const int tid = threadIdx.x;
  __shared__ float red[2];
  float4 v = make_float4(0.f, 0.f, 0.f, 0.f);
  float ss = 0.f;
  if (tid < C_ / 4) {
    v = ((const float4*)(X + (size_t)row * C_))[tid];
    ss = v.x * v.x + v.y * v.y + v.z * v.z + v.w * v.w;
  }
  #pragma unroll
  for (int off = 32; off > 0; off >>= 1) ss += __shfl_xor(ss, off);
  if ((tid & 63) == 0) red[tid >> 6] = ss;
  __syncthreads();
  float rs = rsqrtf((red[0] + red[1]) * (1.f / C_) + 1e-5f);
  if (tid < C_ / 4) {
    float4 gg = ((const float4*)g)[tid];
    ushort4v y;
    y.x = f2bf(v.x * rs * gg.x); y.y = f2bf(v.y * rs * gg.y);
    y.z = f2bf(v.z * rs * gg.z); y.w = f2bf(v.w * rs * gg.w);
    *(ushort4v*)(Y + (size_t)row * KP + tid * 4) = y;
  } else if (tid < 120) {
    ushort4v z = {0, 0, 0, 0};
    *(ushort4v*)(Y + (size_t)row * KP + tid * 4) = z;
  }
}

// ---------------- bf16 MFMA GEMM (128x128 tile, 4 waves, dbuf stage-ahead) ----------------
// EPI: 1 = res+bias->f32; 2 = silu->bf16; 3 = res->f32; 4 = QKV scatter (swizzle-baked)
template<int EPI>
__launch_bounds__(256)
__global__ void gemm_mfma(const unsigned short* __restrict__ A,
                          const unsigned short* __restrict__ Bt,
                          float* __restrict__ Cf, unsigned short* __restrict__ Cb,
                          const float* __restrict__ res, const float* __restrict__ bias,
                          int N, int K, int ldc,
                          unsigned short* __restrict__ Kb2, unsigned short* __restrict__ Vt2) {
  __shared__ __align__(16) unsigned short As[2][4096];
  __shared__ __align__(16) unsigned short Bs[2][4096];
  const int tid = threadIdx.x;
  const int w = tid >> 6, lane = tid & 63;
  const int bm = blockIdx.x * 128, bn = blockIdx.y * 128;

  const int q = lane >> 2;
  const int g = (lane & 3) ^ ((lane >> 3) & 3);
  const int r0 = w * 32 + q;
  const unsigned short* ga0 = A + (size_t)(bm + r0) * K + g * 8;
  const unsigned short* ga1 = ga0 + (size_t)16 * K;
  const unsigned short* gb0 = Bt + (size_t)(bn + r0) * K + g * 8;
  const unsigned short* gb1 = gb0 + (size_t)16 * K;

  const int fr = lane & 15;
  const int gp = (lane >> 4) ^ ((lane >> 1) & 3);
  const int wr = (w >> 1) * 64, wc = (w & 1) * 64;
  int aoff[4], boff[4];
  #pragma unroll
  for (int m = 0; m < 4; ++m) aoff[m] = (wr + m * 16 + fr) * 32 + gp * 8;
  #pragma unroll
  for (int n = 0; n < 4; ++n) boff[n] = (wc + n * 16 + fr) * 32 + gp * 8;

  f32x4 acc[4][4];
  #pragma unroll
  for (int m = 0; m < 4; ++m)
    #pragma unroll
    for (int n = 0; n < 4; ++n) acc[m][n] = (f32x4){0.f, 0.f, 0.f, 0.f};

#define STAGE(BUF, KO) do { \
    load_lds16(ga0 + (KO), &As[BUF][w * 1024]); \
    load_lds16(ga1 + (KO), &As[BUF][w * 1024 + 512]); \
    load_lds16(gb0 + (KO), &Bs[BUF][w * 1024]); \
    load_lds16(gb1 + (KO), &Bs[BUF][w * 1024 + 512]); } while (0)

#define COMPUTE(BUF) do { \
    short8 af[4], bf[4]; \
    _Pragma("unroll") for (int m = 0; m < 4; ++m) af[m] = *(const short8*)(&As[BUF][0] + aoff[m]); \
    _Pragma("unroll") for (int n = 0; n < 4; ++n) bf[n] = *(const short8*)(&Bs[BUF][0] + boff[n]); \
    _Pragma("unroll") for (int m = 0; m < 4; ++m) \
      _Pragma("unroll") for (int n = 0; n < 4; ++n) \
        acc[m][n] = __builtin_amdgcn_mfma_f32_16x16x32_bf16(af[m], bf[n], acc[m][n], 0, 0, 0); \
  } while (0)

  STAGE(0, 0);
  __syncthreads();
  int k0 = 0;
  for (; k0 + 64 <= K; k0 += 64) {
    STAGE(1, k0 + 32);
    COMPUTE(0);
    __syncthreads();
    if (k0 + 64 < K) STAGE(0, k0 + 64);
    COMPUTE(1);
    __syncthreads();
  }
  if (k0 < K) COMPUTE(0);   // odd tail (buffer 0 staged by last iteration)
#undef STAGE
#undef COMPUTE

  const int crow0 = bm + wr + (lane >> 4) * 4;
  const int ccol0 = bn + wc + fr;
  #pragma unroll
  for (int n = 0; n < 4; ++n) {
    const int col = ccol0 + n * 16;
    if (col >= N) continue;
    #pragma unroll
    for (int m = 0; m < 4; ++m) {
      #pragma unroll
      for (int r = 0; r < 4; ++r) {
        const int row = crow0 + m * 16 + r;
        const size_t o = (size_t)row * ldc + col;
        float v = acc[m][n][r];
        if (EPI == 1) Cf[o] = res[o] + v + bias[col];
        else if (EPI == 2) Cb[o] = f2bf(v / (1.f + __expf(-v)));
        else if (EPI == 3) Cf[o] = res[o] + v;
        else if (EPI == 4) {
          // scatter to Qb(Cb)/Kb2/Vt2 with swizzles baked
          int which = col / C_;
          int hd = col - which * C_;
          int hh = hd / D_;
          int d = hd - hh * D_;
          unsigned short bv = f2bf(v);
          if (which < 2) {
            unsigned short* dst = (which == 0) ? Cb : Kb2;
            int pg = (d >> 3) ^ ((row >> 1) & 3);
            size_t base = (size_t)row * 512 + hh * 32;
            dst[base + pg * 8 + (d & 7)] = bv;
            if (d == 28) {            // zero the 3 pad slots (same granule)
              dst[base + pg * 8 + 5] = 0;
              dst[base + pg * 8 + 6] = 0;
              dst[base + pg * 8 + 7] = 0;
            }
          } else {
            int bb = row >> 9, tt = row & 511;
            int pg = ((tt >> 3) & 7) ^ (d & 7);
            Vt2[((size_t)((bb * 16 + hh) * 32 + d)) * 512 + (tt & ~63) + pg * 8 + (tt & 7)] = bv;
          }
        }
      }
    }
  }
}

// ---------------- MFMA flash attention ----------------
// block = 64 q rows of one (b,h); 2 waves (wave = 32-q strip); s-tiles of 64, dbuf.
// blk decode: bh = blk & 255, qt = blk >> 8  (keeps all q-blocks of a bh on one XCD).
// S^T = mfma32x32x16(K, Q^T): lane owns q = lane&31 -> per-lane online softmax.
// O^T = mfma(V^T, P^T): P^T frag built in-register (cvt_pk + permlane32_swap).
__launch_bounds__(128)
__global__ void attn_mfma(const unsigned short* __restrict__ Qb,
                          const unsigned short* __restrict__ Kb,
                          const unsigned short* __restrict__ Vt,
                          const float* __restrict__ pos_emb,
                          unsigned short* __restrict__ Ob) {
  __shared__ __align__(16) unsigned short Qs[2048];     // [64][32]
  __shared__ __align__(16) unsigned short Ks[2][2048];  // [64][32]
  __shared__ __align__(16) unsigned short Vs[2][2048];  // [32][64]
  __shared__ __align__(16) float pes[512];
  const int blk = blockIdx.x;
  const int bh = blk & 255, qt = blk >> 8;
  const int b = bh >> 4, h = bh & 15;
  const int tid = threadIdx.x;
  const int w = tid >> 6, lane = tid & 63;
  const int l31 = lane & 31, hi = lane >> 5;
  const int qb = qt * 64;

  const char* gq = (const char*)Qb + ((size_t)(b * 512 + qb) * 512 + h * 32) * 2;
  const char* gk = (const char*)Kb + ((size_t)(b * 512) * 512 + h * 32) * 2;
  const char* gv = (const char*)Vt + ((size_t)(bh * 32) * 512) * 2;

  // prologue staging: Q (4KB), pe (2KB), tile0 K/V (4KB each); 128 thr, 2 calls each
  #pragma unroll
  for (int j = 0; j < 2; ++j) {
    const int ci = (w * 2 + j) * 64 + lane;
    load_lds16(gq + (size_t)(ci >> 2) * 1024 + (lane & 3) * 16, (char*)Qs + (w * 2 + j) * 1024);
    load_lds16(gk + (size_t)(ci >> 2) * 1024 + (lane & 3) * 16, (char*)Ks[0] + (w * 2 + j) * 1024);
    load_lds16(gv + (size_t)(ci >> 3) * 1024 + (lane & 7) * 16, (char*)Vs[0] + (w * 2 + j) * 1024);
  }
  load_lds16((const char*)pos_emb + h * 2048 + tid * 16, (char*)pes + w * 1024);
  __syncthreads();

  // hoist Q fragments (B-slot: lane holds Q[q=lane&31][d=hi*8+j+16kc])
  const int qrow = w * 32 + l31;
  short8 qf[2];
  #pragma unroll
  for (int kc = 0; kc < 2; ++kc) {
    int pg = (hi + 2 * kc) ^ ((qrow >> 1) & 3);
    qf[kc] = *(const short8*)(Qs + qrow * 32 + pg * 8);
  }

  const int t = qb + w * 32 + l31;
  const int nt = qt + 1;                     // tiles (both waves compute all of them)
  const float scale2 = 0.18569533817705186f * 1.4426950408889634f;  // 29^-.5 * log2e
  f32x16 oacc;
  #pragma unroll
  for (int r = 0; r < 16; ++r) oacc[r] = 0.f;
  float m_run = -1e30f, l_run = 0.f;

  for (int si = 0; si < nt; ++si) {
    const int c = si & 1;
    if (si + 1 < nt) {  // prefetch next tile into buf c^1
      const int sb = (si + 1) * 64;
      #pragma unroll
      for (int j = 0; j < 2; ++j) {
        const int ci = (w * 2 + j) * 64 + lane;
        load_lds16(gk + (size_t)(sb + (ci >> 2)) * 1024 + (lane & 3) * 16,
                   (char*)Ks[c ^ 1] + (w * 2 + j) * 1024);
        load_lds16(gv + (size_t)(ci >> 3) * 1024 + sb * 2 + (lane & 7) * 16,
                   (char*)Vs[c ^ 1] + (w * 2 + j) * 1024);
      }
    }
    {
      const int sbase = si * 64;
      f32x16 sc[2];
      #pragma unroll
      for (int sf = 0; sf < 2; ++sf) {
        int srow = 32 * sf + l31;
        f32x16 a;
        #pragma unroll
        for (int r = 0; r < 16; ++r) a[r] = 0.f;
        #pragma unroll
        for (int kc = 0; kc < 2; ++kc) {
          int pg = (hi + 2 * kc) ^ ((srow >> 1) & 3);
          short8 kf = *(const short8*)(&Ks[c][0] + srow * 32 + pg * 8);
          a = __builtin_amdgcn_mfma_f32_32x32x16_bf16(kf, qf[kc], a, 0, 0, 0);
        }
        sc[sf] = a;
      }
      const bool edge = (si == nt - 1);
      float mt = -1e30f;
      #pragma unroll
      for (int sf = 0; sf < 2; ++sf)
        #pragma unroll
        for (int r = 0; r < 16; ++r) {
          int s_abs = sbase + 32 * sf + ((r & 3) + 8 * (r >> 2)) + 4 * hi;
          int idx = t - s_abs;
          float v;
          if (edge) {
            float bias = pes[idx < 0 ? 0 : idx];
            v = (sc[sf][r] + bias) * scale2;
            if (idx < 0) v = -1e30f;
          } else {
            v = (sc[sf][r] + pes[idx]) * scale2;
          }
          sc[sf][r] = v;
          mt = fmaxf(mt, v);
        }
      mt = fmaxf(mt, __shfl_xor(mt, 32));
      if (mt > m_run + 11.5f) {   // defer-max (T13), exp2 space
        float corr = exp2f(m_run - mt);
        l_run *= corr;
        #pragma unroll
        for (int r = 0; r < 16; ++r) oacc[r] *= corr;
        m_run = mt;
      }
      float ls = 0.f;
      #pragma unroll
      for (int sf = 0; sf < 2; ++sf)
        #pragma unroll
        for (int r = 0; r < 16; ++r) {
          float p = exp2f(sc[sf][r] - m_run);
          sc[sf][r] = p;
          ls += p;
        }
      l_run += ls + __shfl_xor(ls, 32);
      // P^T fragments: per 16-s chunk kc: 4 bf16x2 words via cvt_pk + permlane32_swap.
      // permlane32_swap(vdst,vsrc): new vdst=[vdst_lo|vsrc_lo], new vsrc=[vdst_hi|vsrc_hi]
      unsigned pw[4][4];
      #pragma unroll
      for (int sf = 0; sf < 2; ++sf)
        #pragma unroll
        for (int kk = 0; kk < 2; ++kk) {
          const int kc = sf * 2 + kk;
          const int rb = kk * 8;
          unsigned pk01, pk23, pk45, pk67;
          CVTPK(pk01, sc[sf][rb + 0], sc[sf][rb + 1]);
          CVTPK(pk23, sc[sf][rb + 2], sc[sf][rb + 3]);
          CVTPK(pk45, sc[sf][rb + 4], sc[sf][rb + 5]);
          CVTPK(pk67, sc[sf][rb + 6], sc[sf][rb + 7]);
          asm volatile("v_permlane32_swap_b32 %0, %1" : "+v"(pk01), "+v"(pk45));
          asm volatile("v_permlane32_swap_b32 %0, %1" : "+v"(pk23), "+v"(pk67));
          pw[kc][0] = pk01; pw[kc][1] = pk23; pw[kc][2] = pk45; pw[kc][3] = pk67;
        }
      // PV: O^T += V^T · P^T
      #pragma unroll
      for (int kc = 0; kc < 4; ++kc) {
        int pg = (2 * kc + hi) ^ (l31 & 7);
        short8 vf = *(const short8*)(&Vs[c][0] + l31 * 64 + pg * 8);
        union { unsigned u[4]; short8 s8; } pu;
        pu.u[0] = pw[kc][0]; pu.u[1] = pw[kc][1]; pu.u[2] = pw[kc][2]; pu.u[3] = pw[kc][3];
        oacc = __builtin_amdgcn_mfma_f32_32x32x16_bf16(vf, pu.s8, oacc, 0, 0, 0);
      }
    }
    __syncthreads();
  }

  const float inv = 1.f / l_run;
  #pragma unroll
  for (int r = 0; r < 16; ++r) {
    int d = (r & 3) + 8 * (r >> 2) + 4 * hi;
    if (d < D_)
      Ob[(size_t)(b * 512 + t) * KP + h * D_ + d] = f2bf(oacc[r] * inv);
  }
  if (h == 15 && tid < 64) {  // zero ob pad cols 464..479 (NaN safety)
    char* p = (char*)(Ob + (size_t)(b * 512 + qb + tid) * KP + C_);
    *(uint4*)p = make_uint4(0, 0, 0, 0);
    *(uint4*)(p + 16) = make_uint4(0, 0, 0, 0);
  }
}

extern "C" void kernel_launch(void* const* d_in, const int* in_sizes, int n_in,
                              void* d_out, int out_size, void* d_ws, size_t ws_size,
                              hipStream_t stream) {
  const float* x       = (const float*)d_in[0];
  const float* wq      = (const float*)d_in[2];
  const float* wk      = (const float*)d_in[3];
  const float* wv      = (const float*)d_in[4];
  const float* pos_emb = (const float*)d_in[5];
  const float* w_proj  = (const float*)d_in[6];
  const float* b_proj  = (const float*)d_in[7];
  const float* g1      = (const float*)d_in[8];
  const float* g2      = (const float*)d_in[9];
  const float* w1      = (const float*)d_in[10];
  const float* w2      = (const float*)d_in[11];
  float* out = (float*)d_out;

  char* cur = (char*)d_ws;
  auto alloc = [&](size_t bytes) { char* p = cur; cur += (bytes + 255) & ~(size_t)255; return p; };
  unsigned short* Wqkvt = (unsigned short*)alloc((size_t)NQKV_P * KP * 2);
  unsigned short* Wprt  = (unsigned short*)alloc((size_t)NPC * KP * 2);
  unsigned short* W1t   = (unsigned short*)alloc((size_t)C4P * KP * 2);
  unsigned short* W2t   = (unsigned short*)alloc((size_t)NPC * C4 * 2);
  unsigned short* h1b   = (unsigned short*)alloc((size_t)BT_ * KP * 2);
  unsigned short* ob    = (unsigned short*)alloc((size_t)BT_ * KP * 2);
  unsigned short* ffb   = (unsigned short*)alloc((size_t)BT_ * C4 * 2);
  unsigned short* Qbuf  = (unsigned short*)alloc((size_t)BT_ * 512 * 2);
  unsigned short* Kbuf  = (unsigned short*)alloc((size_t)BT_ * 512 * 2);
  unsigned short* Vtb   = (unsigned short*)alloc((size_t)BT_ * 512 * 2);

  prep_wqkvt<<<(NQKV_P * KP + 255) / 256, 256, 0, stream>>>(wq, wk, wv, Wqkvt);
  prep_wt<<<(NPC * KP + 255) / 256, 256, 0, stream>>>(w_proj, Wprt, C_, C_, KP, NPC * KP);
  prep_wt<<<(C4P * KP + 255) / 256, 256, 0, stream>>>(w1, W1t, C4, C_, KP, C4P * KP);
  prep_wt<<<(NPC * C4 + 255) / 256, 256, 0, stream>>>(w2, W2t, C_, C4, C4, NPC * C4);

  rmsnorm_bf16<<<BT_, 128, 0, stream>>>(x, g1, h1b);
  gemm_mfma<4><<<dim3(BT_ / 128, NQKV_P / 128), 256, 0, stream>>>(
      h1b, Wqkvt, nullptr, Qbuf, nullptr, nullptr, NQKV, KP, 0, Kbuf, Vtb);
  attn_mfma<<<B_ * H_ * 8, 128, 0, stream>>>(Qbuf, Kbuf, Vtb, pos_emb, ob);
  gemm_mfma<1><<<dim3(BT_ / 128, NPC / 128), 256, 0, stream>>>(
      ob, Wprt, out, nullptr, x, b_proj, C_, KP, C_, nullptr, nullptr);
  rmsnorm_bf16<<<BT_, 128, 0, stream>>>(out, g2, h1b);
  gemm_mfma<2><<<dim3(BT_ / 128, C4P / 128), 256, 0, stream>>>(
      h1b, W1t, nullptr, ffb, nullptr, nullptr, C4, KP, C4, nullptr, nullptr);
  gemm_mfma<3><<<dim3(BT_ / 128, NPC / 128), 256, 0, stream>>>(
      ffb, W2t, out, nullptr, out, nullptr, C_, C4, C_, nullptr, nullptr);
}

// Round 6
// 188.780 us; speedup vs baseline: 4.3856x; 1.0342x over previous
//
#include <hip/hip_runtime.h>
#include <math.h>

#define B_ 16
#define T_ 512
#define C_ 464
#define H_ 16
#define D_ 29
#define BT_ 8192
#define NQKV 1392
#define NQKV_P 1408
#define KP 480        // 464 padded to multiple of 32
#define C4 1856       // 4*C
#define C4P 1920
#define NPC 512

typedef __attribute__((ext_vector_type(8))) short short8;
typedef __attribute__((ext_vector_type(4))) float f32x4;
typedef __attribute__((ext_vector_type(16))) float f32x16;
typedef __attribute__((ext_vector_type(4))) unsigned short ushort4v;

static __device__ __forceinline__ unsigned short f2bf(float f) {
  union { float f; unsigned u; } v; v.f = f;
  unsigned r = v.u + 0x7FFFu + ((v.u >> 16) & 1u);
  return (unsigned short)(r >> 16);
}

static __device__ __forceinline__ void load_lds16(const void* g, void* l) {
  __builtin_amdgcn_global_load_lds((const __attribute__((address_space(1))) unsigned int*)g,
                                   (__attribute__((address_space(3))) unsigned int*)l,
                                   16, 0, 0);
}

#define CVTPK(dst, a, b) asm("v_cvt_pk_bf16_f32 %0, %1, %2" : "=v"(dst) : "v"(a), "v"(b))

// ---------------- weight prep ----------------
__global__ void prep_wqkvt(const float* __restrict__ wq, const float* __restrict__ wk,
                           const float* __restrict__ wv, unsigned short* __restrict__ W) {
  int idx = blockIdx.x * 256 + threadIdx.x;
  if (idx >= NQKV_P * KP) return;
  int n = idx / KP, k = idx - n * KP;
  float val = 0.f;
  if (n < NQKV && k < C_) {
    int which = n / C_;
    int hd = n - which * C_;
    int h = hd / D_, d = hd - h * D_;
    const float* s = (which == 0) ? wq : (which == 1) ? wk : wv;
    val = s[((size_t)h * C_ + k) * D_ + d];
  }
  W[idx] = f2bf(val);
}

__global__ void prep_wt(const float* __restrict__ src, unsigned short* __restrict__ dst,
                        int N, int K, int Kp, int total) {
  int idx = blockIdx.x * 256 + threadIdx.x;
  if (idx >= total) return;
  int n = idx / Kp, k = idx - n * Kp;
  float val = (k < K && n < N) ? src[(size_t)k * N + n] : 0.f;
  dst[idx] = f2bf(val);
}

// ---------------- rmsnorm: f32 [8192][464] -> bf16 [8192][480] ----------------
__launch_bounds__(128)
__global__ void rmsnorm_bf16(const float* __restrict__ X, const float* __restrict__ g,
                             unsigned short* __restrict__ Y) {
  const int row = blockIdx.x;
  const int tid = threadIdx.x;
  __shared__ float red[2];
  float4 v = make_float4(0.f, 0.f, 0.f, 0.f);
  float ss = 0.f;
  if (tid < C_ / 4) {
    v = ((const float4*)(X + (size_t)row * C_))[tid];
    ss = v.x * v.x + v.y * v.y + v.z * v.z + v.w * v.w;
  }
  #pragma unroll
  for (int off = 32; off > 0; off >>= 1) ss += __shfl_xor(ss, off);
  if ((tid & 63) == 0) red[tid >> 6] = ss;
  __syncthreads();
  float rs = rsqrtf((red[0] + red[1]) * (1.f / C_) + 1e-5f);
  if (tid < C_ / 4) {
    float4 gg = ((const float4*)g)[tid];
    ushort4v y;
    y.x = f2bf(v.x * rs * gg.x); y.y = f2bf(v.y * rs * gg.y);
    y.z = f2bf(v.z * rs * gg.z); y.w = f2bf(v.w * rs * gg.w);
    *(ushort4v*)(Y + (size_t)row * KP + tid * 4) = y;
  } else if (tid < 120) {
    ushort4v z = {0, 0, 0, 0};
    *(ushort4v*)(Y + (size_t)row * KP + tid * 4) = z;
  }
}

// ---------------- bf16 MFMA GEMM (128x128 tile, 4 waves, 3-deep counted-vmcnt pipe) ---
// One raw s_barrier per K-step; vmcnt(4) in steady state (never 0 mid-loop);
// stage for tile t+2 issued AFTER barrier t (buffer read at t-1 is drained by then).
// EPI: 1 = res+bias->f32; 2 = silu->bf16; 3 = res->f32; 4 = QKV scatter (swizzle-baked)
template<int EPI>
__launch_bounds__(256)
__global__ void gemm_mfma(const unsigned short* __restrict__ A,
                          const unsigned short* __restrict__ Bt,
                          float* __restrict__ Cf, unsigned short* __restrict__ Cb,
                          const float* __restrict__ res, const float* __restrict__ bias,
                          int N, int K, int ldc,
                          unsigned short* __restrict__ Kb2, unsigned short* __restrict__ Vt2) {
  __shared__ __align__(16) unsigned short As[3][4096];
  __shared__ __align__(16) unsigned short Bs[3][4096];
  const int tid = threadIdx.x;
  const int w = tid >> 6, lane = tid & 63;
  const int bm = blockIdx.x * 128, bn = blockIdx.y * 128;

  const int q = lane >> 2;
  const int g = (lane & 3) ^ ((lane >> 3) & 3);
  const int r0 = w * 32 + q;
  const unsigned short* ga0 = A + (size_t)(bm + r0) * K + g * 8;
  const unsigned short* ga1 = ga0 + (size_t)16 * K;
  const unsigned short* gb0 = Bt + (size_t)(bn + r0) * K + g * 8;
  const unsigned short* gb1 = gb0 + (size_t)16 * K;

  const int fr = lane & 15;
  const int gp = (lane >> 4) ^ ((lane >> 1) & 3);
  const int wr = (w >> 1) * 64, wc = (w & 1) * 64;
  int aoff[4], boff[4];
  #pragma unroll
  for (int m = 0; m < 4; ++m) aoff[m] = (wr + m * 16 + fr) * 32 + gp * 8;
  #pragma unroll
  for (int n = 0; n < 4; ++n) boff[n] = (wc + n * 16 + fr) * 32 + gp * 8;

  f32x4 acc[4][4];
  #pragma unroll
  for (int m = 0; m < 4; ++m)
    #pragma unroll
    for (int n = 0; n < 4; ++n) acc[m][n] = (f32x4){0.f, 0.f, 0.f, 0.f};

#define STAGE(BUF, KO) do { \
    load_lds16(ga0 + (KO), &As[BUF][w * 1024]); \
    load_lds16(ga1 + (KO), &As[BUF][w * 1024 + 512]); \
    load_lds16(gb0 + (KO), &Bs[BUF][w * 1024]); \
    load_lds16(gb1 + (KO), &Bs[BUF][w * 1024 + 512]); } while (0)

#define COMPUTE(BUF) do { \
    short8 af[4], bf[4]; \
    _Pragma("unroll") for (int m = 0; m < 4; ++m) af[m] = *(const short8*)(&As[BUF][0] + aoff[m]); \
    _Pragma("unroll") for (int n = 0; n < 4; ++n) bf[n] = *(const short8*)(&Bs[BUF][0] + boff[n]); \
    _Pragma("unroll") for (int m = 0; m < 4; ++m) \
      _Pragma("unroll") for (int n = 0; n < 4; ++n) \
        acc[m][n] = __builtin_amdgcn_mfma_f32_16x16x32_bf16(af[m], bf[n], acc[m][n], 0, 0, 0); \
  } while (0)

  const int nk = K >> 5;
  STAGE(0, 0);
  STAGE(1, 32);
  for (int t = 0; t < nk; ++t) {
    if (t + 1 < nk) {
      asm volatile("s_waitcnt vmcnt(4)" ::: "memory");   // oldest 4 = buf[t]'s loads
    } else {
      asm volatile("s_waitcnt vmcnt(0)" ::: "memory");   // last tile: drain
    }
    asm volatile("s_waitcnt lgkmcnt(0)" ::: "memory");   // ds_reads of t-1 drained
    __builtin_amdgcn_s_barrier();
    __builtin_amdgcn_sched_barrier(0);
    if (t + 2 < nk) STAGE((t + 2) % 3, (t + 2) * 32);    // overwrites buf read at t-1
    COMPUTE(t % 3);
  }
#undef STAGE
#undef COMPUTE

  const int crow0 = bm + wr + (lane >> 4) * 4;
  const int ccol0 = bn + wc + fr;
  #pragma unroll
  for (int n = 0; n < 4; ++n) {
    const int col = ccol0 + n * 16;
    if (col >= N) continue;
    #pragma unroll
    for (int m = 0; m < 4; ++m) {
      #pragma unroll
      for (int r = 0; r < 4; ++r) {
        const int row = crow0 + m * 16 + r;
        const size_t o = (size_t)row * ldc + col;
        float v = acc[m][n][r];
        if (EPI == 1) Cf[o] = res[o] + v + bias[col];
        else if (EPI == 2) Cb[o] = f2bf(v / (1.f + __expf(-v)));
        else if (EPI == 3) Cf[o] = res[o] + v;
        else if (EPI == 4) {
          // scatter to Qb(Cb)/Kb2/Vt2 with swizzles baked
          int which = col / C_;
          int hd = col - which * C_;
          int hh = hd / D_;
          int d = hd - hh * D_;
          unsigned short bv = f2bf(v);
          if (which < 2) {
            unsigned short* dst = (which == 0) ? Cb : Kb2;
            int pg = (d >> 3) ^ ((row >> 1) & 3);
            size_t base = (size_t)row * 512 + hh * 32;
            dst[base + pg * 8 + (d & 7)] = bv;
            if (d == 28) {            // zero the 3 pad slots (same granule)
              dst[base + pg * 8 + 5] = 0;
              dst[base + pg * 8 + 6] = 0;
              dst[base + pg * 8 + 7] = 0;
            }
          } else {
            int bb = row >> 9, tt = row & 511;
            int pg = ((tt >> 3) & 7) ^ (d & 7);
            Vt2[((size_t)((bb * 16 + hh) * 32 + d)) * 512 + (tt & ~63) + pg * 8 + (tt & 7)] = bv;
          }
        }
      }
    }
  }
}

// ---------------- MFMA flash attention ----------------
// block = 64 q rows of one (b,h); 2 waves (wave = 32-q strip); s-tiles of 64, dbuf.
// blk decode: bh = blk & 255, qt = blk >> 8  (keeps all q-blocks of a bh on one XCD).
// S^T = mfma32x32x16(K, Q^T): lane owns q = lane&31 -> per-lane online softmax.
// O^T = mfma(V^T, P^T): P^T frag built in-register (cvt_pk + permlane32_swap).
__launch_bounds__(128)
__global__ void attn_mfma(const unsigned short* __restrict__ Qb,
                          const unsigned short* __restrict__ Kb,
                          const unsigned short* __restrict__ Vt,
                          const float* __restrict__ pos_emb,
                          unsigned short* __restrict__ Ob) {
  __shared__ __align__(16) unsigned short Qs[2048];     // [64][32]
  __shared__ __align__(16) unsigned short Ks[2][2048];  // [64][32]
  __shared__ __align__(16) unsigned short Vs[2][2048];  // [32][64]
  __shared__ __align__(16) float pes[512];
  const int blk = blockIdx.x;
  const int bh = blk & 255, qt = blk >> 8;
  const int b = bh >> 4, h = bh & 15;
  const int tid = threadIdx.x;
  const int w = tid >> 6, lane = tid & 63;
  const int l31 = lane & 31, hi = lane >> 5;
  const int qb = qt * 64;

  const char* gq = (const char*)Qb + ((size_t)(b * 512 + qb) * 512 + h * 32) * 2;
  const char* gk = (const char*)Kb + ((size_t)(b * 512) * 512 + h * 32) * 2;
  const char* gv = (const char*)Vt + ((size_t)(bh * 32) * 512) * 2;

  // prologue staging: Q (4KB), pe (2KB), tile0 K/V (4KB each); 128 thr, 2 calls each
  #pragma unroll
  for (int j = 0; j < 2; ++j) {
    const int ci = (w * 2 + j) * 64 + lane;
    load_lds16(gq + (size_t)(ci >> 2) * 1024 + (lane & 3) * 16, (char*)Qs + (w * 2 + j) * 1024);
    load_lds16(gk + (size_t)(ci >> 2) * 1024 + (lane & 3) * 16, (char*)Ks[0] + (w * 2 + j) * 1024);
    load_lds16(gv + (size_t)(ci >> 3) * 1024 + (lane & 7) * 16, (char*)Vs[0] + (w * 2 + j) * 1024);
  }
  load_lds16((const char*)pos_emb + h * 2048 + tid * 16, (char*)pes + w * 1024);
  __syncthreads();

  // hoist Q fragments (B-slot: lane holds Q[q=lane&31][d=hi*8+j+16kc])
  const int qrow = w * 32 + l31;
  short8 qf[2];
  #pragma unroll
  for (int kc = 0; kc < 2; ++kc) {
    int pg = (hi + 2 * kc) ^ ((qrow >> 1) & 3);
    qf[kc] = *(const short8*)(Qs + qrow * 32 + pg * 8);
  }

  const int t = qb + w * 32 + l31;
  const int nt = qt + 1;                     // tiles (both waves compute all of them)
  const float scale2 = 0.18569533817705186f * 1.4426950408889634f;  // 29^-.5 * log2e
  f32x16 oacc;
  #pragma unroll
  for (int r = 0; r < 16; ++r) oacc[r] = 0.f;
  float m_run = -1e30f, l_run = 0.f;

  for (int si = 0; si < nt; ++si) {
    const int c = si & 1;
    if (si + 1 < nt) {  // prefetch next tile into buf c^1
      const int sb = (si + 1) * 64;
      #pragma unroll
      for (int j = 0; j < 2; ++j) {
        const int ci = (w * 2 + j) * 64 + lane;
        load_lds16(gk + (size_t)(sb + (ci >> 2)) * 1024 + (lane & 3) * 16,
                   (char*)Ks[c ^ 1] + (w * 2 + j) * 1024);
        load_lds16(gv + (size_t)(ci >> 3) * 1024 + sb * 2 + (lane & 7) * 16,
                   (char*)Vs[c ^ 1] + (w * 2 + j) * 1024);
      }
    }
    {
      const int sbase = si * 64;
      f32x16 sc[2];
      #pragma unroll
      for (int sf = 0; sf < 2; ++sf) {
        int srow = 32 * sf + l31;
        f32x16 a;
        #pragma unroll
        for (int r = 0; r < 16; ++r) a[r] = 0.f;
        #pragma unroll
        for (int kc = 0; kc < 2; ++kc) {
          int pg = (hi + 2 * kc) ^ ((srow >> 1) & 3);
          short8 kf = *(const short8*)(&Ks[c][0] + srow * 32 + pg * 8);
          a = __builtin_amdgcn_mfma_f32_32x32x16_bf16(kf, qf[kc], a, 0, 0, 0);
        }
        sc[sf] = a;
      }
      const bool edge = (si == nt - 1);
      float mt = -1e30f;
      #pragma unroll
      for (int sf = 0; sf < 2; ++sf)
        #pragma unroll
        for (int r = 0; r < 16; ++r) {
          int s_abs = sbase + 32 * sf + ((r & 3) + 8 * (r >> 2)) + 4 * hi;
          int idx = t - s_abs;
          float v;
          if (edge) {
            float bias = pes[idx < 0 ? 0 : idx];
            v = (sc[sf][r] + bias) * scale2;
            if (idx < 0) v = -1e30f;
          } else {
            v = (sc[sf][r] + pes[idx]) * scale2;
          }
          sc[sf][r] = v;
          mt = fmaxf(mt, v);
        }
      mt = fmaxf(mt, __shfl_xor(mt, 32));
      if (mt > m_run + 11.5f) {   // defer-max (T13), exp2 space
        float corr = exp2f(m_run - mt);
        l_run *= corr;
        #pragma unroll
        for (int r = 0; r < 16; ++r) oacc[r] *= corr;
        m_run = mt;
      }
      float ls = 0.f;
      #pragma unroll
      for (int sf = 0; sf < 2; ++sf)
        #pragma unroll
        for (int r = 0; r < 16; ++r) {
          float p = exp2f(sc[sf][r] - m_run);
          sc[sf][r] = p;
          ls += p;
        }
      l_run += ls + __shfl_xor(ls, 32);
      // P^T fragments: per 16-s chunk kc: 4 bf16x2 words via cvt_pk + permlane32_swap.
      // permlane32_swap(vdst,vsrc): new vdst=[vdst_lo|vsrc_lo], new vsrc=[vdst_hi|vsrc_hi]
      unsigned pw[4][4];
      #pragma unroll
      for (int sf = 0; sf < 2; ++sf)
        #pragma unroll
        for (int kk = 0; kk < 2; ++kk) {
          const int kc = sf * 2 + kk;
          const int rb = kk * 8;
          unsigned pk01, pk23, pk45, pk67;
          CVTPK(pk01, sc[sf][rb + 0], sc[sf][rb + 1]);
          CVTPK(pk23, sc[sf][rb + 2], sc[sf][rb + 3]);
          CVTPK(pk45, sc[sf][rb + 4], sc[sf][rb + 5]);
          CVTPK(pk67, sc[sf][rb + 6], sc[sf][rb + 7]);
          asm volatile("v_permlane32_swap_b32 %0, %1" : "+v"(pk01), "+v"(pk45));
          asm volatile("v_permlane32_swap_b32 %0, %1" : "+v"(pk23), "+v"(pk67));
          pw[kc][0] = pk01; pw[kc][1] = pk23; pw[kc][2] = pk45; pw[kc][3] = pk67;
        }
      // PV: O^T += V^T · P^T
      #pragma unroll
      for (int kc = 0; kc < 4; ++kc) {
        int pg = (2 * kc + hi) ^ (l31 & 7);
        short8 vf = *(const short8*)(&Vs[c][0] + l31 * 64 + pg * 8);
        union { unsigned u[4]; short8 s8; } pu;
        pu.u[0] = pw[kc][0]; pu.u[1] = pw[kc][1]; pu.u[2] = pw[kc][2]; pu.u[3] = pw[kc][3];
        oacc = __builtin_amdgcn_mfma_f32_32x32x16_bf16(vf, pu.s8, oacc, 0, 0, 0);
      }
    }
    __syncthreads();
  }

  const float inv = 1.f / l_run;
  #pragma unroll
  for (int r = 0; r < 16; ++r) {
    int d = (r & 3) + 8 * (r >> 2) + 4 * hi;
    if (d < D_)
      Ob[(size_t)(b * 512 + t) * KP + h * D_ + d] = f2bf(oacc[r] * inv);
  }
  if (h == 15 && tid < 64) {  // zero ob pad cols 464..479 (NaN safety)
    char* p = (char*)(Ob + (size_t)(b * 512 + qb + tid) * KP + C_);
    *(uint4*)p = make_uint4(0, 0, 0, 0);
    *(uint4*)(p + 16) = make_uint4(0, 0, 0, 0);
  }
}

extern "C" void kernel_launch(void* const* d_in, const int* in_sizes, int n_in,
                              void* d_out, int out_size, void* d_ws, size_t ws_size,
                              hipStream_t stream) {
  const float* x       = (const float*)d_in[0];
  const float* wq      = (const float*)d_in[2];
  const float* wk      = (const float*)d_in[3];
  const float* wv      = (const float*)d_in[4];
  const float* pos_emb = (const float*)d_in[5];
  const float* w_proj  = (const float*)d_in[6];
  const float* b_proj  = (const float*)d_in[7];
  const float* g1      = (const float*)d_in[8];
  const float* g2      = (const float*)d_in[9];
  const float* w1      = (const float*)d_in[10];
  const float* w2      = (const float*)d_in[11];
  float* out = (float*)d_out;

  char* cur = (char*)d_ws;
  auto alloc = [&](size_t bytes) { char* p = cur; cur += (bytes + 255) & ~(size_t)255; return p; };
  unsigned short* Wqkvt = (unsigned short*)alloc((size_t)NQKV_P * KP * 2);
  unsigned short* Wprt  = (unsigned short*)alloc((size_t)NPC * KP * 2);
  unsigned short* W1t   = (unsigned short*)alloc((size_t)C4P * KP * 2);
  unsigned short* W2t   = (unsigned short*)alloc((size_t)NPC * C4 * 2);
  unsigned short* h1b   = (unsigned short*)alloc((size_t)BT_ * KP * 2);
  unsigned short* ob    = (unsigned short*)alloc((size_t)BT_ * KP * 2);
  unsigned short* ffb   = (unsigned short*)alloc((size_t)BT_ * C4 * 2);
  unsigned short* Qbuf  = (unsigned short*)alloc((size_t)BT_ * 512 * 2);
  unsigned short* Kbuf  = (unsigned short*)alloc((size_t)BT_ * 512 * 2);
  unsigned short* Vtb   = (unsigned short*)alloc((size_t)BT_ * 512 * 2);

  prep_wqkvt<<<(NQKV_P * KP + 255) / 256, 256, 0, stream>>>(wq, wk, wv, Wqkvt);
  prep_wt<<<(NPC * KP + 255) / 256, 256, 0, stream>>>(w_proj, Wprt, C_, C_, KP, NPC * KP);
  prep_wt<<<(C4P * KP + 255) / 256, 256, 0, stream>>>(w1, W1t, C4, C_, KP, C4P * KP);
  prep_wt<<<(NPC * C4 + 255) / 256, 256, 0, stream>>>(w2, W2t, C_, C4, C4, NPC * C4);

  rmsnorm_bf16<<<BT_, 128, 0, stream>>>(x, g1, h1b);
  gemm_mfma<4><<<dim3(BT_ / 128, NQKV_P / 128), 256, 0, stream>>>(
      h1b, Wqkvt, nullptr, Qbuf, nullptr, nullptr, NQKV, KP, 0, Kbuf, Vtb);
  attn_mfma<<<B_ * H_ * 8, 128, 0, stream>>>(Qbuf, Kbuf, Vtb, pos_emb, ob);
  gemm_mfma<1><<<dim3(BT_ / 128, NPC / 128), 256, 0, stream>>>(
      ob, Wprt, out, nullptr, x, b_proj, C_, KP, C_, nullptr, nullptr);
  rmsnorm_bf16<<<BT_, 128, 0, stream>>>(out, g2, h1b);
  gemm_mfma<2><<<dim3(BT_ / 128, C4P / 128), 256, 0, stream>>>(
      h1b, W1t, nullptr, ffb, nullptr, nullptr, C4, KP, C4, nullptr, nullptr);
  gemm_mfma<3><<<dim3(BT_ / 128, NPC / 128), 256, 0, stream>>>(
      ffb, W2t, out, nullptr, out, nullptr, C_, C4, C_, nullptr, nullptr);
}